// Round 10
// baseline (122.433 us; speedup 1.0000x reference)
//
#include <hip/hip_runtime.h>
#include <hip/hip_bf16.h>
#include <math.h>

#define HID   128
#define TPB   256      // 4 waves per block, 64 rows per wave -> 256 rows per block-tile
#define TROWS 256
#define NBLK  512      // persistent grid (2 blocks/CU)

typedef __attribute__((ext_vector_type(8))) short        short8v;   // 8 bf16
typedef __attribute__((ext_vector_type(4))) float        f32x4;
typedef __attribute__((ext_vector_type(4))) unsigned int uint4v;

#define MFMA(a, b, c) __builtin_amdgcn_mfma_f32_16x16x32_bf16((a), (b), (c), 0, 0, 0)
#define SCHED_FENCE() __builtin_amdgcn_sched_barrier(0)

__device__ __forceinline__ unsigned int pk2bf(float lo, float hi) {
    unsigned short a = __builtin_bit_cast(unsigned short, __float2bfloat16(lo));
    unsigned short b = __builtin_bit_cast(unsigned short, __float2bfloat16(hi));
    return (unsigned int)a | ((unsigned int)b << 16);
}
__device__ __forceinline__ f32x4 relu4(f32x4 v) {
    f32x4 r;
    r.x = fmaxf(v.x, 0.f); r.y = fmaxf(v.y, 0.f);
    r.z = fmaxf(v.z, 0.f); r.w = fmaxf(v.w, 0.f);
    return r;
}

// 2 waves/EU -> 256-reg unified budget: 128 AGPR (layer-2 acc) + <=~118 VGPR peak.
__global__ __launch_bounds__(TPB, 2)
void stress_kernel(const float* __restrict__ F,
                   const float* __restrict__ W1, const float* __restrict__ b1,
                   const float* __restrict__ W2, const float* __restrict__ b2,
                   const float* __restrict__ W3, const float* __restrict__ b3,
                   float* __restrict__ out, int N)
{
    // ---- LDS (43.5 KB -> 2 blocks/CU) ----
    __shared__ uint4v sA2[2048];   // W2^T A-frags: [(jt*4+ks)*64 + lane]
    __shared__ uint4v sA3[256];    // W3^T A-frags: [ks2*64 + lane]
    __shared__ f32x4  sY[TPB];     // per-wave y transpose buffer (4 KB)
    __shared__ __align__(16) float sW1[3 * HID];
    __shared__ __align__(16) float sb1[HID];
    __shared__ __align__(16) float sb2[HID];

    const int tid  = threadIdx.x;
    const int lane = tid & 63;
    const int wid  = tid >> 6;
    const int g    = lane >> 4;     // lane group 0..3
    const int lr   = lane & 15;

    // ---- one-time per-block weight staging / swizzling ----
    for (int e = tid; e < 2048; e += TPB) {
        int l = e & 63, ks = (e >> 6) & 3, jt = e >> 8;
        int k0 = 8 * (l >> 4) + 32 * ks;
        int j  = (l & 15) + 16 * jt;
        uint4v v;
        v.x = pk2bf(W2[(k0 + 0) * HID + j], W2[(k0 + 1) * HID + j]);
        v.y = pk2bf(W2[(k0 + 2) * HID + j], W2[(k0 + 3) * HID + j]);
        v.z = pk2bf(W2[(k0 + 4) * HID + j], W2[(k0 + 5) * HID + j]);
        v.w = pk2bf(W2[(k0 + 6) * HID + j], W2[(k0 + 7) * HID + j]);
        sA2[e] = v;
    }
    for (int e = tid; e < 256; e += TPB) {
        int l = e & 63, ks2 = e >> 6;
        int gg = l >> 4, t = l & 15;
        float w0  = (t < 4) ? W3[(4 * gg + 0 + 16 * (2 * ks2 + 0)) * 4 + t] : 0.f;
        float w1_ = (t < 4) ? W3[(4 * gg + 1 + 16 * (2 * ks2 + 0)) * 4 + t] : 0.f;
        float w2_ = (t < 4) ? W3[(4 * gg + 2 + 16 * (2 * ks2 + 0)) * 4 + t] : 0.f;
        float w3_ = (t < 4) ? W3[(4 * gg + 3 + 16 * (2 * ks2 + 0)) * 4 + t] : 0.f;
        float w4  = (t < 4) ? W3[(4 * gg + 0 + 16 * (2 * ks2 + 1)) * 4 + t] : 0.f;
        float w5  = (t < 4) ? W3[(4 * gg + 1 + 16 * (2 * ks2 + 1)) * 4 + t] : 0.f;
        float w6  = (t < 4) ? W3[(4 * gg + 2 + 16 * (2 * ks2 + 1)) * 4 + t] : 0.f;
        float w7  = (t < 4) ? W3[(4 * gg + 3 + 16 * (2 * ks2 + 1)) * 4 + t] : 0.f;
        uint4v v;
        v.x = pk2bf(w0, w1_); v.y = pk2bf(w2_, w3_);
        v.z = pk2bf(w4, w5);  v.w = pk2bf(w6, w7);
        sA3[e] = v;
    }
    for (int i = tid; i < 3 * HID; i += TPB) sW1[i] = W1[i];
    for (int i = tid; i < HID; i += TPB)     { sb1[i] = b1[i]; sb2[i] = b2[i]; }
    __syncthreads();

    const f32x4* pW1 = (const f32x4*)sW1;
    const f32x4* pB1 = (const f32x4*)sb1;
    const f32x4* pB2 = (const f32x4*)sb2;

    // persistent hoists: W3 frags (16 VGPR)
    const short8v a3f_0 = __builtin_bit_cast(short8v, sA3[0 * 64 + lane]);
    const short8v a3f_1 = __builtin_bit_cast(short8v, sA3[1 * 64 + lane]);
    const short8v a3f_2 = __builtin_bit_cast(short8v, sA3[2 * 64 + lane]);
    const short8v a3f_3 = __builtin_bit_cast(short8v, sA3[3 * 64 + lane]);

    const int nTiles = (N + TROWS - 1) / TROWS;
    const int tile0  = blockIdx.x;

    // prefetch F for the first tile (each lane owns one row)
    f32x4 fv = {0.f, 0.f, 0.f, 0.f};
    {
        const int n = tile0 * TROWS + wid * 64 + lane;
        if (tile0 < nTiles && n < N) fv = ((const f32x4*)F)[n];
    }

    for (int tile = tile0; tile < nTiles; tile += gridDim.x) {
        const int nbase = tile * TROWS + wid * 64;

        // ---- prologue (all 64 lanes): invariants + polar R for own row ----
        const float fa = fv.x, fb = fv.y, fc = fv.z, fd = fv.w;
        float x0, x1, x2, R00, R01, R10, R11;
        {
            const float J   = fa * fd - fb * fc;
            const float ss  = fa * fa + fb * fb + fc * fc + fd * fd;
            const float sgn = (J >= 0.f) ? 1.f : -1.f;
            const float r   = sqrtf(fmaxf(ss + 2.f * fabsf(J), 1e-30f));
            const float inv = 1.f / r;
            x0 = r - 2.f; x1 = ss - 1.f; x2 = J - 1.f;
            R00 = (fa + sgn * fd) * inv; R01 = (fb - sgn * fc) * inv;
            R10 = (fc - sgn * fb) * inv; R11 = (fd + sgn * fa) * inv;
        }
        // broadcast x per row-tile: x_RT_i = x_i of row RT*16+lr
        const float x_0_0 = __shfl(x0,      lr, 64), x_0_1 = __shfl(x1,      lr, 64), x_0_2 = __shfl(x2,      lr, 64);
        const float x_1_0 = __shfl(x0, 16 + lr, 64), x_1_1 = __shfl(x1, 16 + lr, 64), x_1_2 = __shfl(x2, 16 + lr, 64);
        const float x_2_0 = __shfl(x0, 32 + lr, 64), x_2_1 = __shfl(x1, 32 + lr, 64), x_2_2 = __shfl(x2, 32 + lr, 64);
        const float x_3_0 = __shfl(x0, 48 + lr, 64), x_3_1 = __shfl(x1, 48 + lr, 64), x_3_2 = __shfl(x2, 48 + lr, 64);
        SCHED_FENCE();

        // ---- layer-2 accumulators: 8 jt x 4 rt (128 regs, AGPR half) ----
        #define ACCDECL(JT) f32x4 acc_##JT##_0 = {0.f,0.f,0.f,0.f}, acc_##JT##_1 = {0.f,0.f,0.f,0.f}, \
                                  acc_##JT##_2 = {0.f,0.f,0.f,0.f}, acc_##JT##_3 = {0.f,0.f,0.f,0.f};
        ACCDECL(0) ACCDECL(1) ACCDECL(2) ACCDECL(3)
        ACCDECL(4) ACCDECL(5) ACCDECL(6) ACCDECL(7)
        #undef ACCDECL

        // HBM_RT: build one B-frag then immediately consume with 8 MFMAs.
        // bfr lifetime ~1 region-quarter -> peak pressure ~118 VGPR (no spill);
        // scheduler may overlap HB(RT+1) VALU with RT's MFMAs (same region).
        #define HBM_RT(RT) {                                                          \
            const f32x4 hlo = relu4(blo + w0lo * x_##RT##_0 + w1lo * x_##RT##_1 + w2lo * x_##RT##_2); \
            const f32x4 hhi = relu4(bhi + w0hi * x_##RT##_0 + w1hi * x_##RT##_1 + w2hi * x_##RT##_2); \
            uint4v u;                                                                 \
            u.x = pk2bf(hlo.x, hlo.y); u.y = pk2bf(hlo.z, hlo.w);                     \
            u.z = pk2bf(hhi.x, hhi.y); u.w = pk2bf(hhi.z, hhi.w);                     \
            const short8v bf = __builtin_bit_cast(short8v, u);                        \
            __builtin_amdgcn_s_setprio(1);                                            \
            acc_0_##RT = MFMA(af_0, bf, acc_0_##RT);                                  \
            acc_1_##RT = MFMA(af_1, bf, acc_1_##RT);                                  \
            acc_2_##RT = MFMA(af_2, bf, acc_2_##RT);                                  \
            acc_3_##RT = MFMA(af_3, bf, acc_3_##RT);                                  \
            acc_4_##RT = MFMA(af_4, bf, acc_4_##RT);                                  \
            acc_5_##RT = MFMA(af_5, bf, acc_5_##RT);                                  \
            acc_6_##RT = MFMA(af_6, bf, acc_6_##RT);                                  \
            acc_7_##RT = MFMA(af_7, bf, acc_7_##RT);                                  \
            __builtin_amdgcn_s_setprio(0);                                            \
        }
        #define KSREGION(KS) {                                                        \
            const short8v af_0 = __builtin_bit_cast(short8v, sA2[(0*4+(KS))*64+lane]);\
            const short8v af_1 = __builtin_bit_cast(short8v, sA2[(1*4+(KS))*64+lane]);\
            const short8v af_2 = __builtin_bit_cast(short8v, sA2[(2*4+(KS))*64+lane]);\
            const short8v af_3 = __builtin_bit_cast(short8v, sA2[(3*4+(KS))*64+lane]);\
            const short8v af_4 = __builtin_bit_cast(short8v, sA2[(4*4+(KS))*64+lane]);\
            const short8v af_5 = __builtin_bit_cast(short8v, sA2[(5*4+(KS))*64+lane]);\
            const short8v af_6 = __builtin_bit_cast(short8v, sA2[(6*4+(KS))*64+lane]);\
            const short8v af_7 = __builtin_bit_cast(short8v, sA2[(7*4+(KS))*64+lane]);\
            const int q = 2 * g + 8 * (KS);                                           \
            const f32x4 w0lo = pW1[q],      w0hi = pW1[q + 1];                        \
            const f32x4 w1lo = pW1[32 + q], w1hi = pW1[32 + q + 1];                   \
            const f32x4 w2lo = pW1[64 + q], w2hi = pW1[64 + q + 1];                   \
            const f32x4 blo  = pB1[q],      bhi  = pB1[q + 1];                        \
            HBM_RT(0) HBM_RT(1) HBM_RT(2) HBM_RT(3)                                   \
        } SCHED_FENCE();

        KSREGION(0)
        // next-tile F prefetch issues at the top of the KS1 region
        {
            const int tn = tile + gridDim.x;
            const int nn = tn * TROWS + wid * 64 + lane;
            fv = (f32x4){0.f, 0.f, 0.f, 0.f};
            if (tn < nTiles && nn < N) fv = ((const f32x4*)F)[nn];
        }
        KSREGION(1)
        KSREGION(2)
        KSREGION(3)
        #undef KSREGION
        #undef HBM_RT

        // ---- layer 3: one merged region (8 b2 reads up front, 16 MFMA) ----
        f32x4 accY_0 = {0.f,0.f,0.f,0.f}, accY_1 = {0.f,0.f,0.f,0.f},
              accY_2 = {0.f,0.f,0.f,0.f}, accY_3 = {0.f,0.f,0.f,0.f};
        {
            const f32x4 ba0 = pB2[g +  0], bb0 = pB2[g +  4];
            const f32x4 ba1 = pB2[g +  8], bb1 = pB2[g + 12];
            const f32x4 ba2 = pB2[g + 16], bb2 = pB2[g + 20];
            const f32x4 ba3 = pB2[g + 24], bb3 = pB2[g + 28];
            #define L3R(RT, JA, JB, KS2) {                                            \
                const f32x4 ha = relu4(acc_##JA##_##RT + ba##KS2);                    \
                const f32x4 hb = relu4(acc_##JB##_##RT + bb##KS2);                    \
                uint4v u;                                                             \
                u.x = pk2bf(ha.x, ha.y); u.y = pk2bf(ha.z, ha.w);                     \
                u.z = pk2bf(hb.x, hb.y); u.w = pk2bf(hb.z, hb.w);                     \
                accY_##RT = MFMA(a3f_##KS2, __builtin_bit_cast(short8v, u), accY_##RT); \
            }
            #define L3K(KS2, JA, JB) \
                L3R(0, JA, JB, KS2) L3R(1, JA, JB, KS2) L3R(2, JA, JB, KS2) L3R(3, JA, JB, KS2)
            L3K(0, 0, 1) L3K(1, 2, 3) L3K(2, 4, 5) L3K(3, 6, 7)
            #undef L3K
            #undef L3R
        }
        SCHED_FENCE();

        // ---- epilogue: transpose y via per-wave LDS, then lane-parallel ----
        // lanes 0..15 hold y[0..3] of row RT*16+lr in accY_RT; route row r's y
        // to lane r so every lane finishes its OWN row with its OWN F/R.
        if (lane < 16) {
            sY[wid * 64 +  0 + lr] = accY_0;
            sY[wid * 64 + 16 + lr] = accY_1;
            sY[wid * 64 + 32 + lr] = accY_2;
            sY[wid * 64 + 48 + lr] = accY_3;
        }
        {
            const f32x4 yv = sY[wid * 64 + lane];   // same-wave LDS: no barrier
            const int nn = nbase + lane;
            if (nn < N) {
                const float y0 = yv.x, y1 = yv.y, y2 = yv.z, y3 = yv.w;
                const float s01 = 0.5f * (y1 + y2);
                const float P00 = R00 * y0  + R01 * s01;
                const float P01 = R00 * s01 + R01 * y3;
                const float P10 = R10 * y0  + R11 * s01;
                const float P11 = R10 * s01 + R11 * y3;
                f32x4 o;
                o.x = P00 * fa + P01 * fb;   // cauchy = P @ F^T
                o.y = P00 * fc + P01 * fd;
                o.z = P10 * fa + P11 * fb;
                o.w = P10 * fc + P11 * fd;
                ((f32x4*)out)[nn] = o;
            }
        }
        SCHED_FENCE();
    }
}

extern "C" void kernel_launch(void* const* d_in, const int* in_sizes, int n_in,
                              void* d_out, int out_size, void* d_ws, size_t ws_size,
                              hipStream_t stream) {
    const float* F  = (const float*)d_in[0];
    const float* W1 = (const float*)d_in[1];
    const float* b1 = (const float*)d_in[2];
    const float* W2 = (const float*)d_in[3];
    const float* b2 = (const float*)d_in[4];
    const float* W3 = (const float*)d_in[5];
    const float* b3 = (const float*)d_in[6];
    float* out = (float*)d_out;
    const int N = in_sizes[0] / 4;

    const int nTiles = (N + TROWS - 1) / TROWS;
    int grid = nTiles < NBLK ? nTiles : NBLK;
    stress_kernel<<<dim3(grid), dim3(TPB), 0, stream>>>(F, W1, b1, W2, b2, W3, b3, out, N);
}

// Round 11
// 77.797 us; speedup vs baseline: 1.5737x; 1.5737x over previous
//
#include <hip/hip_runtime.h>
#include <hip/hip_bf16.h>
#include <math.h>

#define HID   128
#define TPB   256      // 4 waves per block, 64 rows per wave -> 256 rows per block-tile
#define TROWS 256
#define NBLK  512      // persistent grid (2 blocks/CU)

typedef __attribute__((ext_vector_type(8))) short        short8v;   // 8 bf16
typedef __attribute__((ext_vector_type(4))) float        f32x4;
typedef __attribute__((ext_vector_type(4))) unsigned int uint4v;

#define MFMA(a, b, c) __builtin_amdgcn_mfma_f32_16x16x32_bf16((a), (b), (c), 0, 0, 0)
#define SCHED_FENCE() __builtin_amdgcn_sched_barrier(0)

__device__ __forceinline__ unsigned int pk2bf(float lo, float hi) {
    unsigned short a = __builtin_bit_cast(unsigned short, __float2bfloat16(lo));
    unsigned short b = __builtin_bit_cast(unsigned short, __float2bfloat16(hi));
    return (unsigned int)a | ((unsigned int)b << 16);
}
__device__ __forceinline__ f32x4 relu4(f32x4 v) {
    f32x4 r;
    r.x = fmaxf(v.x, 0.f); r.y = fmaxf(v.y, 0.f);
    r.z = fmaxf(v.z, 0.f); r.w = fmaxf(v.w, 0.f);
    return r;
}

// 2 waves/EU -> 256-reg unified budget: 128 AGPR (layer-2 acc) + <=~113 VGPR peak.
__global__ __launch_bounds__(TPB, 2)
void stress_kernel(const float* __restrict__ F,
                   const float* __restrict__ W1, const float* __restrict__ b1,
                   const float* __restrict__ W2, const float* __restrict__ b2,
                   const float* __restrict__ W3, const float* __restrict__ b3,
                   float* __restrict__ out, int N)
{
    // ---- LDS (43.5 KB -> 2 blocks/CU) ----
    __shared__ uint4v sA2[2048];   // W2^T A-frags: [(jt*4+ks)*64 + lane]
    __shared__ uint4v sA3[256];    // W3^T A-frags: [ks2*64 + lane]
    __shared__ f32x4  sY[TPB];     // per-wave y transpose buffer (4 KB)
    __shared__ __align__(16) float sW1[3 * HID];
    __shared__ __align__(16) float sb1[HID];
    __shared__ __align__(16) float sb2[HID];

    const int tid  = threadIdx.x;
    const int lane = tid & 63;
    const int wid  = tid >> 6;
    const int g    = lane >> 4;     // lane group 0..3
    const int lr   = lane & 15;

    // ---- one-time per-block weight staging / swizzling ----
    for (int e = tid; e < 2048; e += TPB) {
        int l = e & 63, ks = (e >> 6) & 3, jt = e >> 8;
        int k0 = 8 * (l >> 4) + 32 * ks;
        int j  = (l & 15) + 16 * jt;
        uint4v v;
        v.x = pk2bf(W2[(k0 + 0) * HID + j], W2[(k0 + 1) * HID + j]);
        v.y = pk2bf(W2[(k0 + 2) * HID + j], W2[(k0 + 3) * HID + j]);
        v.z = pk2bf(W2[(k0 + 4) * HID + j], W2[(k0 + 5) * HID + j]);
        v.w = pk2bf(W2[(k0 + 6) * HID + j], W2[(k0 + 7) * HID + j]);
        sA2[e] = v;
    }
    for (int e = tid; e < 256; e += TPB) {
        int l = e & 63, ks2 = e >> 6;
        int gg = l >> 4, t = l & 15;
        float w0  = (t < 4) ? W3[(4 * gg + 0 + 16 * (2 * ks2 + 0)) * 4 + t] : 0.f;
        float w1_ = (t < 4) ? W3[(4 * gg + 1 + 16 * (2 * ks2 + 0)) * 4 + t] : 0.f;
        float w2_ = (t < 4) ? W3[(4 * gg + 2 + 16 * (2 * ks2 + 0)) * 4 + t] : 0.f;
        float w3_ = (t < 4) ? W3[(4 * gg + 3 + 16 * (2 * ks2 + 0)) * 4 + t] : 0.f;
        float w4  = (t < 4) ? W3[(4 * gg + 0 + 16 * (2 * ks2 + 1)) * 4 + t] : 0.f;
        float w5  = (t < 4) ? W3[(4 * gg + 1 + 16 * (2 * ks2 + 1)) * 4 + t] : 0.f;
        float w6  = (t < 4) ? W3[(4 * gg + 2 + 16 * (2 * ks2 + 1)) * 4 + t] : 0.f;
        float w7  = (t < 4) ? W3[(4 * gg + 3 + 16 * (2 * ks2 + 1)) * 4 + t] : 0.f;
        uint4v v;
        v.x = pk2bf(w0, w1_); v.y = pk2bf(w2_, w3_);
        v.z = pk2bf(w4, w5);  v.w = pk2bf(w6, w7);
        sA3[e] = v;
    }
    for (int i = tid; i < 3 * HID; i += TPB) sW1[i] = W1[i];
    for (int i = tid; i < HID; i += TPB)     { sb1[i] = b1[i]; sb2[i] = b2[i]; }
    __syncthreads();

    const f32x4* pW1 = (const f32x4*)sW1;
    const f32x4* pB1 = (const f32x4*)sb1;
    const f32x4* pB2 = (const f32x4*)sb2;

    const int nTiles = (N + TROWS - 1) / TROWS;
    const int tile0  = blockIdx.x;

    // prefetch F for the first tile (each lane owns one row)
    f32x4 fv = {0.f, 0.f, 0.f, 0.f};
    {
        const int n = tile0 * TROWS + wid * 64 + lane;
        if (tile0 < nTiles && n < N) fv = ((const f32x4*)F)[n];
    }

    for (int tile = tile0; tile < nTiles; tile += gridDim.x) {
        const int nbase = tile * TROWS + wid * 64;

        // ---- prologue (all 64 lanes): invariants + polar R for own row ----
        const float fa = fv.x, fb = fv.y, fc = fv.z, fd = fv.w;
        float x0, x1, x2, R00, R01, R10, R11;
        {
            const float J   = fa * fd - fb * fc;
            const float ss  = fa * fa + fb * fb + fc * fc + fd * fd;
            const float sgn = (J >= 0.f) ? 1.f : -1.f;
            const float r   = sqrtf(fmaxf(ss + 2.f * fabsf(J), 1e-30f));
            const float inv = 1.f / r;
            x0 = r - 2.f; x1 = ss - 1.f; x2 = J - 1.f;
            R00 = (fa + sgn * fd) * inv; R01 = (fb - sgn * fc) * inv;
            R10 = (fc - sgn * fb) * inv; R11 = (fd + sgn * fa) * inv;
        }
        // broadcast x per row-tile: x_RT_i = x_i of row RT*16+lr
        const float x_0_0 = __shfl(x0,      lr, 64), x_0_1 = __shfl(x1,      lr, 64), x_0_2 = __shfl(x2,      lr, 64);
        const float x_1_0 = __shfl(x0, 16 + lr, 64), x_1_1 = __shfl(x1, 16 + lr, 64), x_1_2 = __shfl(x2, 16 + lr, 64);
        const float x_2_0 = __shfl(x0, 32 + lr, 64), x_2_1 = __shfl(x1, 32 + lr, 64), x_2_2 = __shfl(x2, 32 + lr, 64);
        const float x_3_0 = __shfl(x0, 48 + lr, 64), x_3_1 = __shfl(x1, 48 + lr, 64), x_3_2 = __shfl(x2, 48 + lr, 64);
        SCHED_FENCE();

        // ---- layer-2 accumulators: 8 jt x 4 rt (128 regs, AGPR half) ----
        #define ACCDECL(JT) f32x4 acc_##JT##_0 = {0.f,0.f,0.f,0.f}, acc_##JT##_1 = {0.f,0.f,0.f,0.f}, \
                                  acc_##JT##_2 = {0.f,0.f,0.f,0.f}, acc_##JT##_3 = {0.f,0.f,0.f,0.f};
        ACCDECL(0) ACCDECL(1) ACCDECL(2) ACCDECL(3)
        ACCDECL(4) ACCDECL(5) ACCDECL(6) ACCDECL(7)
        #undef ACCDECL

        #define HB(RT) {                                                              \
            const f32x4 hlo = relu4(blo + w0lo * x_##RT##_0 + w1lo * x_##RT##_1 + w2lo * x_##RT##_2); \
            const f32x4 hhi = relu4(bhi + w0hi * x_##RT##_0 + w1hi * x_##RT##_1 + w2hi * x_##RT##_2); \
            uint4v u;                                                                 \
            u.x = pk2bf(hlo.x, hlo.y); u.y = pk2bf(hlo.z, hlo.w);                     \
            u.z = pk2bf(hhi.x, hhi.y); u.w = pk2bf(hhi.z, hhi.w);                     \
            bfr_##RT = __builtin_bit_cast(short8v, u);                                \
        }
        #define STEP(JT, RT) acc_##JT##_##RT = MFMA(af_##JT, bfr_##RT, acc_##JT##_##RT)

        // KSBLOCK: region A = {W1 reads, af reads, h-build} (af latency hides
        // under ~350cy h-build VALU); region B = pure MFMA. Fence between caps
        // live ranges: A-demand ~113 VGPR, B-demand ~60. Spill-safe.
        #define KSBLOCK(KS) {                                                         \
            short8v af_0, af_1, af_2, af_3, af_4, af_5, af_6, af_7;                   \
            short8v bfr_0, bfr_1, bfr_2, bfr_3;                                       \
            {                                                                         \
                const int q = 2 * g + 8 * (KS);                                       \
                const f32x4 w0lo = pW1[q],      w0hi = pW1[q + 1];                    \
                const f32x4 w1lo = pW1[32 + q], w1hi = pW1[32 + q + 1];               \
                const f32x4 w2lo = pW1[64 + q], w2hi = pW1[64 + q + 1];               \
                const f32x4 blo  = pB1[q],      bhi  = pB1[q + 1];                    \
                af_0 = __builtin_bit_cast(short8v, sA2[(0*4+(KS))*64+lane]);          \
                af_1 = __builtin_bit_cast(short8v, sA2[(1*4+(KS))*64+lane]);          \
                af_2 = __builtin_bit_cast(short8v, sA2[(2*4+(KS))*64+lane]);          \
                af_3 = __builtin_bit_cast(short8v, sA2[(3*4+(KS))*64+lane]);          \
                af_4 = __builtin_bit_cast(short8v, sA2[(4*4+(KS))*64+lane]);          \
                af_5 = __builtin_bit_cast(short8v, sA2[(5*4+(KS))*64+lane]);          \
                af_6 = __builtin_bit_cast(short8v, sA2[(6*4+(KS))*64+lane]);          \
                af_7 = __builtin_bit_cast(short8v, sA2[(7*4+(KS))*64+lane]);          \
                HB(0) HB(1) HB(2) HB(3)                                               \
            }                                                                         \
            SCHED_FENCE();                                                            \
            __builtin_amdgcn_s_setprio(1);                                            \
            STEP(0,0); STEP(0,1); STEP(0,2); STEP(0,3);                               \
            STEP(1,0); STEP(1,1); STEP(1,2); STEP(1,3);                               \
            STEP(2,0); STEP(2,1); STEP(2,2); STEP(2,3);                               \
            STEP(3,0); STEP(3,1); STEP(3,2); STEP(3,3);                               \
            STEP(4,0); STEP(4,1); STEP(4,2); STEP(4,3);                               \
            STEP(5,0); STEP(5,1); STEP(5,2); STEP(5,3);                               \
            STEP(6,0); STEP(6,1); STEP(6,2); STEP(6,3);                               \
            STEP(7,0); STEP(7,1); STEP(7,2); STEP(7,3);                               \
            __builtin_amdgcn_s_setprio(0);                                            \
            SCHED_FENCE();                                                            \
        }

        KSBLOCK(0)
        // next-tile F prefetch: its own tiny region (vmcnt waits only at next use)
        {
            const int tn = tile + gridDim.x;
            const int nn = tn * TROWS + wid * 64 + lane;
            fv = (f32x4){0.f, 0.f, 0.f, 0.f};
            if (tn < nTiles && nn < N) fv = ((const f32x4*)F)[nn];
        }
        KSBLOCK(1)
        KSBLOCK(2)
        KSBLOCK(3)
        #undef KSBLOCK
        #undef STEP
        #undef HB

        // ---- layer 3: ONE region {8 b2 reads + 4 a3f reads, 16 pack+MFMA} ----
        f32x4 accY_0 = {0.f,0.f,0.f,0.f}, accY_1 = {0.f,0.f,0.f,0.f},
              accY_2 = {0.f,0.f,0.f,0.f}, accY_3 = {0.f,0.f,0.f,0.f};
        {
            const f32x4 ba0 = pB2[g +  0], bb0 = pB2[g +  4];
            const f32x4 ba1 = pB2[g +  8], bb1 = pB2[g + 12];
            const f32x4 ba2 = pB2[g + 16], bb2 = pB2[g + 20];
            const f32x4 ba3 = pB2[g + 24], bb3 = pB2[g + 28];
            const short8v a3f_0 = __builtin_bit_cast(short8v, sA3[0 * 64 + lane]);
            const short8v a3f_1 = __builtin_bit_cast(short8v, sA3[1 * 64 + lane]);
            const short8v a3f_2 = __builtin_bit_cast(short8v, sA3[2 * 64 + lane]);
            const short8v a3f_3 = __builtin_bit_cast(short8v, sA3[3 * 64 + lane]);
            #define L3R(RT, JA, JB, KS2) {                                            \
                const f32x4 ha = relu4(acc_##JA##_##RT + ba##KS2);                    \
                const f32x4 hb = relu4(acc_##JB##_##RT + bb##KS2);                    \
                uint4v u;                                                             \
                u.x = pk2bf(ha.x, ha.y); u.y = pk2bf(ha.z, ha.w);                     \
                u.z = pk2bf(hb.x, hb.y); u.w = pk2bf(hb.z, hb.w);                     \
                accY_##RT = MFMA(a3f_##KS2, __builtin_bit_cast(short8v, u), accY_##RT); \
            }
            #define L3K(KS2, JA, JB) \
                L3R(0, JA, JB, KS2) L3R(1, JA, JB, KS2) L3R(2, JA, JB, KS2) L3R(3, JA, JB, KS2)
            L3K(0, 0, 1) L3K(1, 2, 3) L3K(2, 4, 5) L3K(3, 6, 7)
            #undef L3K
            #undef L3R
        }
        SCHED_FENCE();

        // ---- epilogue: transpose y via per-wave LDS, then lane-parallel ----
        if (lane < 16) {
            sY[wid * 64 +  0 + lr] = accY_0;
            sY[wid * 64 + 16 + lr] = accY_1;
            sY[wid * 64 + 32 + lr] = accY_2;
            sY[wid * 64 + 48 + lr] = accY_3;
        }
        {
            const f32x4 yv = sY[wid * 64 + lane];   // same-wave LDS: no barrier
            const int nn = nbase + lane;
            if (nn < N) {
                const float y0 = yv.x, y1 = yv.y, y2 = yv.z, y3 = yv.w;
                const float s01 = 0.5f * (y1 + y2);
                const float P00 = R00 * y0  + R01 * s01;
                const float P01 = R00 * s01 + R01 * y3;
                const float P10 = R10 * y0  + R11 * s01;
                const float P11 = R10 * s01 + R11 * y3;
                f32x4 o;
                o.x = P00 * fa + P01 * fb;   // cauchy = P @ F^T
                o.y = P00 * fc + P01 * fd;
                o.z = P10 * fa + P11 * fb;
                o.w = P10 * fc + P11 * fd;
                ((f32x4*)out)[nn] = o;
            }
        }
        SCHED_FENCE();
    }
}

extern "C" void kernel_launch(void* const* d_in, const int* in_sizes, int n_in,
                              void* d_out, int out_size, void* d_ws, size_t ws_size,
                              hipStream_t stream) {
    const float* F  = (const float*)d_in[0];
    const float* W1 = (const float*)d_in[1];
    const float* b1 = (const float*)d_in[2];
    const float* W2 = (const float*)d_in[3];
    const float* b2 = (const float*)d_in[4];
    const float* W3 = (const float*)d_in[5];
    const float* b3 = (const float*)d_in[6];
    float* out = (float*)d_out;
    const int N = in_sizes[0] / 4;

    const int nTiles = (N + TROWS - 1) / TROWS;
    int grid = nTiles < NBLK ? nTiles : NBLK;
    stress_kernel<<<dim3(grid), dim3(TPB), 0, stream>>>(F, W1, b1, W2, b2, W3, b3, out, N);
}

// Round 12
// 67.458 us; speedup vs baseline: 1.8149x; 1.1533x over previous
//
#include <hip/hip_runtime.h>
#include <hip/hip_bf16.h>
#include <math.h>

#define HID   128
#define TPB   256      // 4 waves per block, 32 rows per wave -> 128 rows per block-tile
#define TROWS 128
#define NBLK  512      // persistent grid (2 blocks/CU)

typedef __attribute__((ext_vector_type(8))) short        short8v;   // 8 bf16
typedef __attribute__((ext_vector_type(4))) float        f32x4;
typedef __attribute__((ext_vector_type(4))) unsigned int uint4v;

#define MFMA(a, b, c) __builtin_amdgcn_mfma_f32_16x16x32_bf16((a), (b), (c), 0, 0, 0)
#define SCHED_FENCE() __builtin_amdgcn_sched_barrier(0)

__device__ __forceinline__ unsigned int pk2bf(float lo, float hi) {
    unsigned short a = __builtin_bit_cast(unsigned short, __float2bfloat16(lo));
    unsigned short b = __builtin_bit_cast(unsigned short, __float2bfloat16(hi));
    return (unsigned int)a | ((unsigned int)b << 16);
}
__device__ __forceinline__ float bfhi(float x) {       // round-trip to bf16
    return __bfloat162float(__float2bfloat16(x));
}
__device__ __forceinline__ f32x4 relu4(f32x4 v) {
    f32x4 r;
    r.x = fmaxf(v.x, 0.f); r.y = fmaxf(v.y, 0.f);
    r.z = fmaxf(v.z, 0.f); r.w = fmaxf(v.w, 0.f);
    return r;
}

// 2 waves/EU -> 256-reg unified budget; peak demand ~175 (72 AGPR + ~103 VGPR).
__global__ __launch_bounds__(TPB, 2)
void stress_kernel(const float* __restrict__ F,
                   const float* __restrict__ W1, const float* __restrict__ b1,
                   const float* __restrict__ W2, const float* __restrict__ b2,
                   const float* __restrict__ W3, const float* __restrict__ b3,
                   float* __restrict__ out, int N)
{
    // ---- LDS (~46.6 KB -> 2 blocks/CU) ----
    __shared__ uint4v sA2[2048];   // 32 KB  W2^T A-frags, slot k = 4g+(b&3)+16*(2ks+(b>>2))
    __shared__ uint4v sA1[512];    //  8 KB  layer-1 A-frags (hi-lo W1 + b1 slots)
    __shared__ uint4v sA3[256];    //  4 KB  W3^T A-frags
    __shared__ f32x4  sY[TROWS];   //  2 KB  per-wave y transpose
    __shared__ __align__(16) float sb2[HID];

    const int tid  = threadIdx.x;
    const int lane = tid & 63;
    const int wid  = tid >> 6;
    const int g    = lane >> 4;     // lane group 0..3
    const int lr   = lane & 15;

    // ---- one-time staging ----
    // sA2: NEW k-slot map matching layer-1's D layout:
    //   slot (g,b,ks) -> k = 4g + (b&3) + 16*(2ks + (b>>2)); A-row j = lr + 16jt
    for (int e = tid; e < 2048; e += TPB) {
        int l = e & 63, ks = (e >> 6) & 3, jt = e >> 8;
        int gg = l >> 4;
        int j  = (l & 15) + 16 * jt;
        #define K2(B) (4 * gg + ((B) & 3) + 16 * (2 * ks + ((B) >> 2)))
        uint4v v;
        v.x = pk2bf(W2[K2(0) * HID + j], W2[K2(1) * HID + j]);
        v.y = pk2bf(W2[K2(2) * HID + j], W2[K2(3) * HID + j]);
        v.z = pk2bf(W2[K2(4) * HID + j], W2[K2(5) * HID + j]);
        v.w = pk2bf(W2[K2(6) * HID + j], W2[K2(7) * HID + j]);
        #undef K2
        sA2[e] = v;
    }
    // sA1: layer-1 A-frags. A-row j = lr+16jt; k-slot c = 8g+b:
    //   c=0..2: W1[c][j] (pk rounds -> Wh) ; c=3..5: W1-Wh (Wl, pairs with xh)
    //   c=6..8: W1 (Wh, pairs with xl)     ; c=9: b1[j] ; c=10: b1 - b1h ; else 0
    for (int e = tid; e < 512; e += TPB) {
        int l = e & 63, jt = e >> 6;
        int gg = l >> 4;
        int j  = (l & 15) + 16 * jt;
        float av[8];
        #pragma unroll
        for (int b = 0; b < 8; ++b) {
            int c = 8 * gg + b;
            float v;
            if      (c < 3)   v = W1[c * HID + j];
            else if (c < 6)   v = W1[(c - 3) * HID + j] - bfhi(W1[(c - 3) * HID + j]);
            else if (c < 9)   v = W1[(c - 6) * HID + j];
            else if (c == 9)  v = b1[j];
            else if (c == 10) v = b1[j] - bfhi(b1[j]);
            else              v = 0.f;
            av[b] = v;
        }
        uint4v v;
        v.x = pk2bf(av[0], av[1]); v.y = pk2bf(av[2], av[3]);
        v.z = pk2bf(av[4], av[5]); v.w = pk2bf(av[6], av[7]);
        sA1[e] = v;
    }
    // sA3: W3^T padded (unchanged slot map = layer-2 D layout)
    for (int e = tid; e < 256; e += TPB) {
        int l = e & 63, ks2 = e >> 6;
        int gg = l >> 4, t = l & 15;
        float w[8];
        #pragma unroll
        for (int b = 0; b < 8; ++b) {
            int j = 4 * gg + (b & 3) + 16 * (2 * ks2 + (b >> 2));
            w[b] = (t < 4) ? W3[j * 4 + t] : 0.f;
        }
        uint4v v;
        v.x = pk2bf(w[0], w[1]); v.y = pk2bf(w[2], w[3]);
        v.z = pk2bf(w[4], w[5]); v.w = pk2bf(w[6], w[7]);
        sA3[e] = v;
    }
    for (int i = tid; i < HID; i += TPB) sb2[i] = b2[i];
    __syncthreads();

    const f32x4* pB2 = (const f32x4*)sb2;
    const f32x4  z4  = {0.f, 0.f, 0.f, 0.f};

    const int nTiles = (N + TROWS - 1) / TROWS;
    const int tile0  = blockIdx.x;

    // prefetch F for the first tile (lanes 0..31 own rows)
    f32x4 fv = z4;
    {
        const int n = tile0 * TROWS + wid * 32 + lane;
        if (lane < 32 && tile0 < nTiles && n < N) fv = ((const f32x4*)F)[n];
    }

    for (int tile = tile0; tile < nTiles; tile += gridDim.x) {
        const int nbase = tile * TROWS + wid * 32;

        // ---- prologue: invariants + polar R (lanes 0..31 own rows) ----
        const float fa = fv.x, fb = fv.y, fc = fv.z, fd = fv.w;
        float x0, x1, x2, R00, R01, R10, R11;
        {
            const float J   = fa * fd - fb * fc;
            const float ss  = fa * fa + fb * fb + fc * fc + fd * fd;
            const float sgn = (J >= 0.f) ? 1.f : -1.f;
            const float r   = sqrtf(fmaxf(ss + 2.f * fabsf(J), 1e-30f));
            const float inv = 1.f / r;
            x0 = r - 2.f; x1 = ss - 1.f; x2 = J - 1.f;
            R00 = (fa + sgn * fd) * inv; R01 = (fb - sgn * fc) * inv;
            R10 = (fc - sgn * fb) * inv; R11 = (fd + sgn * fa) * inv;
        }

        // ---- layer-1 B-frags (hi-lo x + bias-1 slots), one per row-tile ----
        short8v b1f_0, b1f_1;
        #define B1BUILD(RT, DST) {                                                 \
            const float bx0 = __shfl(x0, (RT) * 16 + lr, 64);                      \
            const float bx1 = __shfl(x1, (RT) * 16 + lr, 64);                      \
            const float bx2 = __shfl(x2, (RT) * 16 + lr, 64);                      \
            const float xl0 = bx0 - bfhi(bx0);                                     \
            const float xl1 = bx1 - bfhi(bx1);                                     \
            const float xl2 = bx2 - bfhi(bx2);                                     \
            uint4v u;                                                              \
            u.x = (g == 0) ? pk2bf(bx0, bx1) : ((g == 1) ? pk2bf(xl2, 1.f) : 0u);  \
            u.y = (g == 0) ? pk2bf(bx2, bx0) : ((g == 1) ? pk2bf(1.f, 0.f) : 0u);  \
            u.z = (g == 0) ? pk2bf(bx1, bx2) : 0u;                                 \
            u.w = (g == 0) ? pk2bf(xl0, xl1) : 0u;                                 \
            DST = __builtin_bit_cast(short8v, u);                                  \
        }
        B1BUILD(0, b1f_0) B1BUILD(1, b1f_1)
        #undef B1BUILD
        SCHED_FENCE();

        // ---- layer-2 accumulators: 8 jt x 2 rt (64 regs, AGPR) ----
        #define ACCDECL(JT) f32x4 acc_##JT##_0 = z4, acc_##JT##_1 = z4;
        ACCDECL(0) ACCDECL(1) ACCDECL(2) ACCDECL(3)
        ACCDECL(4) ACCDECL(5) ACCDECL(6) ACCDECL(7)
        #undef ACCDECL

        #define STEP(JT, RT) acc_##JT##_##RT = MFMA(af_##JT, bf_##RT, acc_##JT##_##RT)
        // per-ks region: {a1+af reads | 4 L1-MFMA | relu | pack | 16 L2-MFMA}
        #define KSBLOCK(KS) {                                                         \
            const short8v a1_0 = __builtin_bit_cast(short8v, sA1[(2*(KS)  )*64+lane]);\
            const short8v a1_1 = __builtin_bit_cast(short8v, sA1[(2*(KS)+1)*64+lane]);\
            const short8v af_0 = __builtin_bit_cast(short8v, sA2[(0*4+(KS))*64+lane]);\
            const short8v af_1 = __builtin_bit_cast(short8v, sA2[(1*4+(KS))*64+lane]);\
            const short8v af_2 = __builtin_bit_cast(short8v, sA2[(2*4+(KS))*64+lane]);\
            const short8v af_3 = __builtin_bit_cast(short8v, sA2[(3*4+(KS))*64+lane]);\
            const short8v af_4 = __builtin_bit_cast(short8v, sA2[(4*4+(KS))*64+lane]);\
            const short8v af_5 = __builtin_bit_cast(short8v, sA2[(5*4+(KS))*64+lane]);\
            const short8v af_6 = __builtin_bit_cast(short8v, sA2[(6*4+(KS))*64+lane]);\
            const short8v af_7 = __builtin_bit_cast(short8v, sA2[(7*4+(KS))*64+lane]);\
            const f32x4 h00 = relu4(MFMA(a1_0, b1f_0, z4));  /* (jt=2ks,  rt0) */     \
            const f32x4 h01 = relu4(MFMA(a1_0, b1f_1, z4));  /* (jt=2ks,  rt1) */     \
            const f32x4 h10 = relu4(MFMA(a1_1, b1f_0, z4));  /* (jt=2ks+1,rt0) */     \
            const f32x4 h11 = relu4(MFMA(a1_1, b1f_1, z4));  /* (jt=2ks+1,rt1) */     \
            uint4v u0, u1;                                                            \
            u0.x = pk2bf(h00.x, h00.y); u0.y = pk2bf(h00.z, h00.w);                   \
            u0.z = pk2bf(h10.x, h10.y); u0.w = pk2bf(h10.z, h10.w);                   \
            u1.x = pk2bf(h01.x, h01.y); u1.y = pk2bf(h01.z, h01.w);                   \
            u1.z = pk2bf(h11.x, h11.y); u1.w = pk2bf(h11.z, h11.w);                   \
            const short8v bf_0 = __builtin_bit_cast(short8v, u0);                     \
            const short8v bf_1 = __builtin_bit_cast(short8v, u1);                     \
            __builtin_amdgcn_s_setprio(1);                                            \
            STEP(0,0); STEP(0,1); STEP(1,0); STEP(1,1);                               \
            STEP(2,0); STEP(2,1); STEP(3,0); STEP(3,1);                               \
            STEP(4,0); STEP(4,1); STEP(5,0); STEP(5,1);                               \
            STEP(6,0); STEP(6,1); STEP(7,0); STEP(7,1);                               \
            __builtin_amdgcn_s_setprio(0);                                            \
            SCHED_FENCE();                                                            \
        }

        KSBLOCK(0)
        // next-tile F prefetch rides in its own tiny region
        {
            const int tn = tile + gridDim.x;
            const int nn = tn * TROWS + wid * 32 + lane;
            fv = z4;
            if (lane < 32 && tn < nTiles && nn < N) fv = ((const f32x4*)F)[nn];
        }
        KSBLOCK(1)
        KSBLOCK(2)
        KSBLOCK(3)
        #undef KSBLOCK
        #undef STEP

        // ---- layer 3: one region {b2 frags + a3f reads, 8 pack + 8 MFMA} ----
        f32x4 accY_0 = z4, accY_1 = z4;
        {
            const short8v a3f_0 = __builtin_bit_cast(short8v, sA3[0 * 64 + lane]);
            const short8v a3f_1 = __builtin_bit_cast(short8v, sA3[1 * 64 + lane]);
            const short8v a3f_2 = __builtin_bit_cast(short8v, sA3[2 * 64 + lane]);
            const short8v a3f_3 = __builtin_bit_cast(short8v, sA3[3 * 64 + lane]);
            #define L3K(KS2, JA, JB) {                                                \
                const f32x4 ba = pB2[g + 8 * (KS2)];                                  \
                const f32x4 bb = pB2[g + 8 * (KS2) + 4];                              \
                const f32x4 ha0 = relu4(acc_##JA##_0 + ba);                           \
                const f32x4 hb0 = relu4(acc_##JB##_0 + bb);                           \
                const f32x4 ha1 = relu4(acc_##JA##_1 + ba);                           \
                const f32x4 hb1 = relu4(acc_##JB##_1 + bb);                           \
                uint4v u0, u1;                                                        \
                u0.x = pk2bf(ha0.x, ha0.y); u0.y = pk2bf(ha0.z, ha0.w);               \
                u0.z = pk2bf(hb0.x, hb0.y); u0.w = pk2bf(hb0.z, hb0.w);               \
                u1.x = pk2bf(ha1.x, ha1.y); u1.y = pk2bf(ha1.z, ha1.w);               \
                u1.z = pk2bf(hb1.x, hb1.y); u1.w = pk2bf(hb1.z, hb1.w);               \
                accY_0 = MFMA(a3f_##KS2, __builtin_bit_cast(short8v, u0), accY_0);    \
                accY_1 = MFMA(a3f_##KS2, __builtin_bit_cast(short8v, u1), accY_1);    \
            }
            L3K(0, 0, 1) L3K(1, 2, 3) L3K(2, 4, 5) L3K(3, 6, 7)
            #undef L3K
        }
        SCHED_FENCE();

        // ---- epilogue: same-wave LDS transpose, lanes 0..31 finish own row ----
        if (lane < 16) {
            sY[wid * 32 +  0 + lr] = accY_0;
            sY[wid * 32 + 16 + lr] = accY_1;
        }
        {
            const f32x4 yv = sY[wid * 32 + (lane & 31)];
            const int nn = nbase + lane;
            if (lane < 32 && nn < N) {
                const float y0 = yv.x, y1 = yv.y, y2 = yv.z, y3 = yv.w;
                const float s01 = 0.5f * (y1 + y2);
                const float P00 = R00 * y0  + R01 * s01;
                const float P01 = R00 * s01 + R01 * y3;
                const float P10 = R10 * y0  + R11 * s01;
                const float P11 = R10 * s01 + R11 * y3;
                f32x4 o;
                o.x = P00 * fa + P01 * fb;   // cauchy = P @ F^T
                o.y = P00 * fc + P01 * fd;
                o.z = P10 * fa + P11 * fb;
                o.w = P10 * fc + P11 * fd;
                ((f32x4*)out)[nn] = o;
            }
        }
        SCHED_FENCE();
    }
}

extern "C" void kernel_launch(void* const* d_in, const int* in_sizes, int n_in,
                              void* d_out, int out_size, void* d_ws, size_t ws_size,
                              hipStream_t stream) {
    const float* F  = (const float*)d_in[0];
    const float* W1 = (const float*)d_in[1];
    const float* b1 = (const float*)d_in[2];
    const float* W2 = (const float*)d_in[3];
    const float* b2 = (const float*)d_in[4];
    const float* W3 = (const float*)d_in[5];
    const float* b3 = (const float*)d_in[6];
    float* out = (float*)d_out;
    const int N = in_sizes[0] / 4;

    const int nTiles = (N + TROWS - 1) / TROWS;
    int grid = nTiles < NBLK ? nTiles : NBLK;
    stress_kernel<<<dim3(grid), dim3(TPB), 0, stream>>>(F, W1, b1, W2, b2, W3, b3, out, N);
}

// Round 13
// 65.015 us; speedup vs baseline: 1.8832x; 1.0376x over previous
//
#include <hip/hip_runtime.h>
#include <hip/hip_bf16.h>
#include <math.h>

#define HID   128
#define TPB   256      // 4 waves per block, 32 rows per wave -> 128 rows per block-tile
#define TROWS 128
#define NBLK  768      // persistent grid: 3 blocks/CU (reg 148/wave, LDS 47.6KB -> both fit 3)

typedef __attribute__((ext_vector_type(8))) short        short8v;   // 8 bf16
typedef __attribute__((ext_vector_type(4))) float        f32x4;
typedef __attribute__((ext_vector_type(4))) unsigned int uint4v;

#define MFMA(a, b, c) __builtin_amdgcn_mfma_f32_16x16x32_bf16((a), (b), (c), 0, 0, 0)
#define SCHED_FENCE() __builtin_amdgcn_sched_barrier(0)

__device__ __forceinline__ unsigned int pk2bf(float lo, float hi) {
    unsigned short a = __builtin_bit_cast(unsigned short, __float2bfloat16(lo));
    unsigned short b = __builtin_bit_cast(unsigned short, __float2bfloat16(hi));
    return (unsigned int)a | ((unsigned int)b << 16);
}
__device__ __forceinline__ float bfhi(float x) {       // round-trip to bf16
    return __bfloat162float(__float2bfloat16(x));
}
__device__ __forceinline__ f32x4 relu4(f32x4 v) {
    f32x4 r;
    r.x = fmaxf(v.x, 0.f); r.y = fmaxf(v.y, 0.f);
    r.z = fmaxf(v.z, 0.f); r.w = fmaxf(v.w, 0.f);
    return r;
}

// 2 waves/EU min (allocator headroom); actual alloc 148/wave -> 3 waves/SIMD fit.
__global__ __launch_bounds__(TPB, 2)
void stress_kernel(const float* __restrict__ F,
                   const float* __restrict__ W1, const float* __restrict__ b1,
                   const float* __restrict__ W2, const float* __restrict__ b2,
                   const float* __restrict__ W3, const float* __restrict__ b3,
                   float* __restrict__ out, int N)
{
    // ---- LDS (~46.6 KB -> 3 blocks/CU) ----
    __shared__ uint4v sA2[2048];   // 32 KB  W2^T A-frags, slot k = 4g+(b&3)+16*(2ks+(b>>2))
    __shared__ uint4v sA1[512];    //  8 KB  layer-1 A-frags (hi-lo W1 + b1 slots)
    __shared__ uint4v sA3[256];    //  4 KB  W3^T A-frags
    __shared__ f32x4  sY[TROWS];   //  2 KB  per-wave y transpose
    __shared__ __align__(16) float sb2[HID];

    const int tid  = threadIdx.x;
    const int lane = tid & 63;
    const int wid  = tid >> 6;
    const int g    = lane >> 4;     // lane group 0..3
    const int lr   = lane & 15;

    // ---- one-time staging ----
    // sA2: k-slot map matching layer-1's D layout:
    //   slot (g,b,ks) -> k = 4g + (b&3) + 16*(2ks + (b>>2)); A-row j = lr + 16jt
    for (int e = tid; e < 2048; e += TPB) {
        int l = e & 63, ks = (e >> 6) & 3, jt = e >> 8;
        int gg = l >> 4;
        int j  = (l & 15) + 16 * jt;
        #define K2(B) (4 * gg + ((B) & 3) + 16 * (2 * ks + ((B) >> 2)))
        uint4v v;
        v.x = pk2bf(W2[K2(0) * HID + j], W2[K2(1) * HID + j]);
        v.y = pk2bf(W2[K2(2) * HID + j], W2[K2(3) * HID + j]);
        v.z = pk2bf(W2[K2(4) * HID + j], W2[K2(5) * HID + j]);
        v.w = pk2bf(W2[K2(6) * HID + j], W2[K2(7) * HID + j]);
        #undef K2
        sA2[e] = v;
    }
    // sA1: layer-1 A-frags. A-row j = lr+16jt; k-slot c = 8g+b:
    //   c=0..2: W1[c][j] (pk rounds -> Wh) ; c=3..5: W1-Wh (Wl, pairs with xh)
    //   c=6..8: W1 (Wh, pairs with xl)     ; c=9: b1[j] ; c=10: b1 - b1h ; else 0
    for (int e = tid; e < 512; e += TPB) {
        int l = e & 63, jt = e >> 6;
        int gg = l >> 4;
        int j  = (l & 15) + 16 * jt;
        float av[8];
        #pragma unroll
        for (int b = 0; b < 8; ++b) {
            int c = 8 * gg + b;
            float v;
            if      (c < 3)   v = W1[c * HID + j];
            else if (c < 6)   v = W1[(c - 3) * HID + j] - bfhi(W1[(c - 3) * HID + j]);
            else if (c < 9)   v = W1[(c - 6) * HID + j];
            else if (c == 9)  v = b1[j];
            else if (c == 10) v = b1[j] - bfhi(b1[j]);
            else              v = 0.f;
            av[b] = v;
        }
        uint4v v;
        v.x = pk2bf(av[0], av[1]); v.y = pk2bf(av[2], av[3]);
        v.z = pk2bf(av[4], av[5]); v.w = pk2bf(av[6], av[7]);
        sA1[e] = v;
    }
    // sA3: W3^T padded (slot map = layer-2 D layout)
    for (int e = tid; e < 256; e += TPB) {
        int l = e & 63, ks2 = e >> 6;
        int gg = l >> 4, t = l & 15;
        float w[8];
        #pragma unroll
        for (int b = 0; b < 8; ++b) {
            int j = 4 * gg + (b & 3) + 16 * (2 * ks2 + (b >> 2));
            w[b] = (t < 4) ? W3[j * 4 + t] : 0.f;
        }
        uint4v v;
        v.x = pk2bf(w[0], w[1]); v.y = pk2bf(w[2], w[3]);
        v.z = pk2bf(w[4], w[5]); v.w = pk2bf(w[6], w[7]);
        sA3[e] = v;
    }
    for (int i = tid; i < HID; i += TPB) sb2[i] = b2[i];
    __syncthreads();

    const f32x4* pB2 = (const f32x4*)sb2;
    const f32x4  z4  = {0.f, 0.f, 0.f, 0.f};

    const int nTiles = (N + TROWS - 1) / TROWS;
    const int tile0  = blockIdx.x;

    // prefetch F for the first tile (lanes 0..31 own rows)
    f32x4 fv = z4;
    {
        const int n = tile0 * TROWS + wid * 32 + lane;
        if (lane < 32 && tile0 < nTiles && n < N) fv = ((const f32x4*)F)[n];
    }

    for (int tile = tile0; tile < nTiles; tile += gridDim.x) {
        const int nbase = tile * TROWS + wid * 32;

        // ---- prologue: invariants + polar R (lanes 0..31 own rows) ----
        const float fa = fv.x, fb = fv.y, fc = fv.z, fd = fv.w;
        float x0, x1, x2, R00, R01, R10, R11;
        {
            const float J   = fa * fd - fb * fc;
            const float ss  = fa * fa + fb * fb + fc * fc + fd * fd;
            const float sgn = (J >= 0.f) ? 1.f : -1.f;
            const float r   = sqrtf(fmaxf(ss + 2.f * fabsf(J), 1e-30f));
            const float inv = 1.f / r;
            x0 = r - 2.f; x1 = ss - 1.f; x2 = J - 1.f;
            R00 = (fa + sgn * fd) * inv; R01 = (fb - sgn * fc) * inv;
            R10 = (fc - sgn * fb) * inv; R11 = (fd + sgn * fa) * inv;
        }

        // ---- layer-1 B-frags (hi-lo x + bias-1 slots), one per row-tile ----
        short8v b1f_0, b1f_1;
        #define B1BUILD(RT, DST) {                                                 \
            const float bx0 = __shfl(x0, (RT) * 16 + lr, 64);                      \
            const float bx1 = __shfl(x1, (RT) * 16 + lr, 64);                      \
            const float bx2 = __shfl(x2, (RT) * 16 + lr, 64);                      \
            const float xl0 = bx0 - bfhi(bx0);                                     \
            const float xl1 = bx1 - bfhi(bx1);                                     \
            const float xl2 = bx2 - bfhi(bx2);                                     \
            uint4v u;                                                              \
            u.x = (g == 0) ? pk2bf(bx0, bx1) : ((g == 1) ? pk2bf(xl2, 1.f) : 0u);  \
            u.y = (g == 0) ? pk2bf(bx2, bx0) : ((g == 1) ? pk2bf(1.f, 0.f) : 0u);  \
            u.z = (g == 0) ? pk2bf(bx1, bx2) : 0u;                                 \
            u.w = (g == 0) ? pk2bf(xl0, xl1) : 0u;                                 \
            DST = __builtin_bit_cast(short8v, u);                                  \
        }
        B1BUILD(0, b1f_0) B1BUILD(1, b1f_1)
        #undef B1BUILD
        SCHED_FENCE();

        // ---- layer-2 accumulators: 8 jt x 2 rt (64 regs, AGPR) ----
        #define ACCDECL(JT) f32x4 acc_##JT##_0 = z4, acc_##JT##_1 = z4;
        ACCDECL(0) ACCDECL(1) ACCDECL(2) ACCDECL(3)
        ACCDECL(4) ACCDECL(5) ACCDECL(6) ACCDECL(7)
        #undef ACCDECL

        #define STEP(JT, RT) acc_##JT##_##RT = MFMA(af_##JT, bf_##RT, acc_##JT##_##RT)
        // per-ks region: {a1+af reads | 4 L1-MFMA | relu | pack | 16 L2-MFMA}
        #define KSBLOCK(KS) {                                                         \
            const short8v a1_0 = __builtin_bit_cast(short8v, sA1[(2*(KS)  )*64+lane]);\
            const short8v a1_1 = __builtin_bit_cast(short8v, sA1[(2*(KS)+1)*64+lane]);\
            const short8v af_0 = __builtin_bit_cast(short8v, sA2[(0*4+(KS))*64+lane]);\
            const short8v af_1 = __builtin_bit_cast(short8v, sA2[(1*4+(KS))*64+lane]);\
            const short8v af_2 = __builtin_bit_cast(short8v, sA2[(2*4+(KS))*64+lane]);\
            const short8v af_3 = __builtin_bit_cast(short8v, sA2[(3*4+(KS))*64+lane]);\
            const short8v af_4 = __builtin_bit_cast(short8v, sA2[(4*4+(KS))*64+lane]);\
            const short8v af_5 = __builtin_bit_cast(short8v, sA2[(5*4+(KS))*64+lane]);\
            const short8v af_6 = __builtin_bit_cast(short8v, sA2[(6*4+(KS))*64+lane]);\
            const short8v af_7 = __builtin_bit_cast(short8v, sA2[(7*4+(KS))*64+lane]);\
            const f32x4 h00 = relu4(MFMA(a1_0, b1f_0, z4));  /* (jt=2ks,  rt0) */     \
            const f32x4 h01 = relu4(MFMA(a1_0, b1f_1, z4));  /* (jt=2ks,  rt1) */     \
            const f32x4 h10 = relu4(MFMA(a1_1, b1f_0, z4));  /* (jt=2ks+1,rt0) */     \
            const f32x4 h11 = relu4(MFMA(a1_1, b1f_1, z4));  /* (jt=2ks+1,rt1) */     \
            uint4v u0, u1;                                                            \
            u0.x = pk2bf(h00.x, h00.y); u0.y = pk2bf(h00.z, h00.w);                   \
            u0.z = pk2bf(h10.x, h10.y); u0.w = pk2bf(h10.z, h10.w);                   \
            u1.x = pk2bf(h01.x, h01.y); u1.y = pk2bf(h01.z, h01.w);                   \
            u1.z = pk2bf(h11.x, h11.y); u1.w = pk2bf(h11.z, h11.w);                   \
            const short8v bf_0 = __builtin_bit_cast(short8v, u0);                     \
            const short8v bf_1 = __builtin_bit_cast(short8v, u1);                     \
            __builtin_amdgcn_s_setprio(1);                                            \
            STEP(0,0); STEP(0,1); STEP(1,0); STEP(1,1);                               \
            STEP(2,0); STEP(2,1); STEP(3,0); STEP(3,1);                               \
            STEP(4,0); STEP(4,1); STEP(5,0); STEP(5,1);                               \
            STEP(6,0); STEP(6,1); STEP(7,0); STEP(7,1);                               \
            __builtin_amdgcn_s_setprio(0);                                            \
            SCHED_FENCE();                                                            \
        }

        KSBLOCK(0)
        // next-tile F prefetch rides in its own tiny region
        {
            const int tn = tile + gridDim.x;
            const int nn = tn * TROWS + wid * 32 + lane;
            fv = z4;
            if (lane < 32 && tn < nTiles && nn < N) fv = ((const f32x4*)F)[nn];
        }
        KSBLOCK(1)
        KSBLOCK(2)
        KSBLOCK(3)
        #undef KSBLOCK
        #undef STEP

        // ---- layer 3: one region {b2 frags + a3f reads, 8 pack + 8 MFMA} ----
        f32x4 accY_0 = z4, accY_1 = z4;
        {
            const short8v a3f_0 = __builtin_bit_cast(short8v, sA3[0 * 64 + lane]);
            const short8v a3f_1 = __builtin_bit_cast(short8v, sA3[1 * 64 + lane]);
            const short8v a3f_2 = __builtin_bit_cast(short8v, sA3[2 * 64 + lane]);
            const short8v a3f_3 = __builtin_bit_cast(short8v, sA3[3 * 64 + lane]);
            #define L3K(KS2, JA, JB) {                                                \
                const f32x4 ba = pB2[g + 8 * (KS2)];                                  \
                const f32x4 bb = pB2[g + 8 * (KS2) + 4];                              \
                const f32x4 ha0 = relu4(acc_##JA##_0 + ba);                           \
                const f32x4 hb0 = relu4(acc_##JB##_0 + bb);                           \
                const f32x4 ha1 = relu4(acc_##JA##_1 + ba);                           \
                const f32x4 hb1 = relu4(acc_##JB##_1 + bb);                           \
                uint4v u0, u1;                                                        \
                u0.x = pk2bf(ha0.x, ha0.y); u0.y = pk2bf(ha0.z, ha0.w);               \
                u0.z = pk2bf(hb0.x, hb0.y); u0.w = pk2bf(hb0.z, hb0.w);               \
                u1.x = pk2bf(ha1.x, ha1.y); u1.y = pk2bf(ha1.z, ha1.w);               \
                u1.z = pk2bf(hb1.x, hb1.y); u1.w = pk2bf(hb1.z, hb1.w);               \
                accY_0 = MFMA(a3f_##KS2, __builtin_bit_cast(short8v, u0), accY_0);    \
                accY_1 = MFMA(a3f_##KS2, __builtin_bit_cast(short8v, u1), accY_1);    \
            }
            L3K(0, 0, 1) L3K(1, 2, 3) L3K(2, 4, 5) L3K(3, 6, 7)
            #undef L3K
        }
        SCHED_FENCE();

        // ---- epilogue: same-wave LDS transpose, lanes 0..31 finish own row ----
        if (lane < 16) {
            sY[wid * 32 +  0 + lr] = accY_0;
            sY[wid * 32 + 16 + lr] = accY_1;
        }
        {
            const f32x4 yv = sY[wid * 32 + (lane & 31)];
            const int nn = nbase + lane;
            if (lane < 32 && nn < N) {
                const float y0 = yv.x, y1 = yv.y, y2 = yv.z, y3 = yv.w;
                const float s01 = 0.5f * (y1 + y2);
                const float P00 = R00 * y0  + R01 * s01;
                const float P01 = R00 * s01 + R01 * y3;
                const float P10 = R10 * y0  + R11 * s01;
                const float P11 = R10 * s01 + R11 * y3;
                f32x4 o;
                o.x = P00 * fa + P01 * fb;   // cauchy = P @ F^T
                o.y = P00 * fc + P01 * fd;
                o.z = P10 * fa + P11 * fb;
                o.w = P10 * fc + P11 * fd;
                ((f32x4*)out)[nn] = o;
            }
        }
        SCHED_FENCE();
    }
}

extern "C" void kernel_launch(void* const* d_in, const int* in_sizes, int n_in,
                              void* d_out, int out_size, void* d_ws, size_t ws_size,
                              hipStream_t stream) {
    const float* F  = (const float*)d_in[0];
    const float* W1 = (const float*)d_in[1];
    const float* b1 = (const float*)d_in[2];
    const float* W2 = (const float*)d_in[3];
    const float* b2 = (const float*)d_in[4];
    const float* W3 = (const float*)d_in[5];
    const float* b3 = (const float*)d_in[6];
    float* out = (float*)d_out;
    const int N = in_sizes[0] / 4;

    const int nTiles = (N + TROWS - 1) / TROWS;
    int grid = nTiles < NBLK ? nTiles : NBLK;
    stress_kernel<<<dim3(grid), dim3(TPB), 0, stream>>>(F, W1, b1, W2, b2, W3, b3, out, N);
}

// Round 14
// 54.966 us; speedup vs baseline: 2.2274x; 1.1828x over previous
//
#include <hip/hip_runtime.h>
#include <hip/hip_bf16.h>
#include <math.h>

#define HID   128
#define TPB   256      // 4 waves per block, 32 rows per wave -> 128 rows per block-tile
#define TROWS 128
#define NBLK  768      // persistent grid: 3 blocks/CU

typedef __attribute__((ext_vector_type(8))) short        short8v;   // 8 bf16
typedef __attribute__((ext_vector_type(4))) float        f32x4;
typedef __attribute__((ext_vector_type(4))) unsigned int uint4v;

#define MFMA(a, b, c) __builtin_amdgcn_mfma_f32_16x16x32_bf16((a), (b), (c), 0, 0, 0)
#define SCHED_FENCE() __builtin_amdgcn_sched_barrier(0)

// Native packed f32->bf16 pair conversion (1 VALU inst vs ~13 for the
// software-RNE __float2bfloat16 pair). T12 recipe: no builtin on gfx950.
__device__ __forceinline__ unsigned int pk2bf(float lo, float hi) {
    unsigned int r;
    asm("v_cvt_pk_bf16_f32 %0, %1, %2" : "=v"(r) : "v"(lo), "v"(hi));
    return r;
}
// bf16 round-trip (hi part of hi-lo split): bf16(x) in high 16 bits, 0 low.
__device__ __forceinline__ float bfhi(float x) {
    unsigned int r;
    asm("v_cvt_pk_bf16_f32 %0, %1, %2" : "=v"(r) : "v"(0.f), "v"(x));
    return __builtin_bit_cast(float, r);
}
__device__ __forceinline__ f32x4 relu4(f32x4 v) {
    f32x4 r;
    r.x = fmaxf(v.x, 0.f); r.y = fmaxf(v.y, 0.f);
    r.z = fmaxf(v.z, 0.f); r.w = fmaxf(v.w, 0.f);
    return r;
}

// 2 waves/EU min (allocator headroom); actual alloc ~148/wave -> 3 waves/SIMD fit.
__global__ __launch_bounds__(TPB, 2)
void stress_kernel(const float* __restrict__ F,
                   const float* __restrict__ W1, const float* __restrict__ b1,
                   const float* __restrict__ W2, const float* __restrict__ b2,
                   const float* __restrict__ W3, const float* __restrict__ b3,
                   float* __restrict__ out, int N)
{
    // ---- LDS (~46.6 KB -> 3 blocks/CU) ----
    __shared__ uint4v sA2[2048];   // 32 KB  W2^T A-frags, slot k = 4g+(b&3)+16*(2ks+(b>>2))
    __shared__ uint4v sA1[512];    //  8 KB  layer-1 A-frags (hi-lo W1 + b1 slots)
    __shared__ uint4v sA3[256];    //  4 KB  W3^T A-frags
    __shared__ f32x4  sY[TROWS];   //  2 KB  per-wave y transpose
    __shared__ __align__(16) float sb2[HID];

    const int tid  = threadIdx.x;
    const int lane = tid & 63;
    const int wid  = tid >> 6;
    const int g    = lane >> 4;     // lane group 0..3
    const int lr   = lane & 15;

    // ---- one-time staging ----
    // sA2: k-slot map matching layer-1's D layout:
    //   slot (g,b,ks) -> k = 4g + (b&3) + 16*(2ks + (b>>2)); A-row j = lr + 16jt
    for (int e = tid; e < 2048; e += TPB) {
        int l = e & 63, ks = (e >> 6) & 3, jt = e >> 8;
        int gg = l >> 4;
        int j  = (l & 15) + 16 * jt;
        #define K2(B) (4 * gg + ((B) & 3) + 16 * (2 * ks + ((B) >> 2)))
        uint4v v;
        v.x = pk2bf(W2[K2(0) * HID + j], W2[K2(1) * HID + j]);
        v.y = pk2bf(W2[K2(2) * HID + j], W2[K2(3) * HID + j]);
        v.z = pk2bf(W2[K2(4) * HID + j], W2[K2(5) * HID + j]);
        v.w = pk2bf(W2[K2(6) * HID + j], W2[K2(7) * HID + j]);
        #undef K2
        sA2[e] = v;
    }
    // sA1: layer-1 A-frags. A-row j = lr+16jt; k-slot c = 8g+b:
    //   c=0..2: W1[c][j] (pk rounds -> Wh) ; c=3..5: W1-Wh (Wl, pairs with xh)
    //   c=6..8: W1 (Wh, pairs with xl)     ; c=9: b1[j] ; c=10: b1 - b1h ; else 0
    for (int e = tid; e < 512; e += TPB) {
        int l = e & 63, jt = e >> 6;
        int gg = l >> 4;
        int j  = (l & 15) + 16 * jt;
        float av[8];
        #pragma unroll
        for (int b = 0; b < 8; ++b) {
            int c = 8 * gg + b;
            float v;
            if      (c < 3)   v = W1[c * HID + j];
            else if (c < 6)   v = W1[(c - 3) * HID + j] - bfhi(W1[(c - 3) * HID + j]);
            else if (c < 9)   v = W1[(c - 6) * HID + j];
            else if (c == 9)  v = b1[j];
            else if (c == 10) v = b1[j] - bfhi(b1[j]);
            else              v = 0.f;
            av[b] = v;
        }
        uint4v v;
        v.x = pk2bf(av[0], av[1]); v.y = pk2bf(av[2], av[3]);
        v.z = pk2bf(av[4], av[5]); v.w = pk2bf(av[6], av[7]);
        sA1[e] = v;
    }
    // sA3: W3^T padded (slot map = layer-2 D layout)
    for (int e = tid; e < 256; e += TPB) {
        int l = e & 63, ks2 = e >> 6;
        int gg = l >> 4, t = l & 15;
        float w[8];
        #pragma unroll
        for (int b = 0; b < 8; ++b) {
            int j = 4 * gg + (b & 3) + 16 * (2 * ks2 + (b >> 2));
            w[b] = (t < 4) ? W3[j * 4 + t] : 0.f;
        }
        uint4v v;
        v.x = pk2bf(w[0], w[1]); v.y = pk2bf(w[2], w[3]);
        v.z = pk2bf(w[4], w[5]); v.w = pk2bf(w[6], w[7]);
        sA3[e] = v;
    }
    for (int i = tid; i < HID; i += TPB) sb2[i] = b2[i];
    __syncthreads();

    const f32x4* pB2 = (const f32x4*)sb2;
    const f32x4  z4  = {0.f, 0.f, 0.f, 0.f};

    const int nTiles = (N + TROWS - 1) / TROWS;
    const int tile0  = blockIdx.x;

    // prefetch F for the first tile (lanes 0..31 own rows)
    f32x4 fv = z4;
    {
        const int n = tile0 * TROWS + wid * 32 + lane;
        if (lane < 32 && tile0 < nTiles && n < N) fv = ((const f32x4*)F)[n];
    }

    for (int tile = tile0; tile < nTiles; tile += gridDim.x) {
        const int nbase = tile * TROWS + wid * 32;

        // ---- prologue: invariants + polar R (lanes 0..31 own rows) ----
        const float fa = fv.x, fb = fv.y, fc = fv.z, fd = fv.w;
        float x0, x1, x2, R00, R01, R10, R11;
        {
            const float J   = fa * fd - fb * fc;
            const float ss  = fa * fa + fb * fb + fc * fc + fd * fd;
            const float sgn = (J >= 0.f) ? 1.f : -1.f;
            const float r   = sqrtf(fmaxf(ss + 2.f * fabsf(J), 1e-30f));
            const float inv = 1.f / r;
            x0 = r - 2.f; x1 = ss - 1.f; x2 = J - 1.f;
            R00 = (fa + sgn * fd) * inv; R01 = (fb - sgn * fc) * inv;
            R10 = (fc - sgn * fb) * inv; R11 = (fd + sgn * fa) * inv;
        }

        // ---- layer-1 B-frags (hi-lo x + bias-1 slots), one per row-tile ----
        short8v b1f_0, b1f_1;
        #define B1BUILD(RT, DST) {                                                 \
            const float bx0 = __shfl(x0, (RT) * 16 + lr, 64);                      \
            const float bx1 = __shfl(x1, (RT) * 16 + lr, 64);                      \
            const float bx2 = __shfl(x2, (RT) * 16 + lr, 64);                      \
            const float xl0 = bx0 - bfhi(bx0);                                     \
            const float xl1 = bx1 - bfhi(bx1);                                     \
            const float xl2 = bx2 - bfhi(bx2);                                     \
            uint4v u;                                                              \
            u.x = (g == 0) ? pk2bf(bx0, bx1) : ((g == 1) ? pk2bf(xl2, 1.f) : 0u);  \
            u.y = (g == 0) ? pk2bf(bx2, bx0) : ((g == 1) ? pk2bf(1.f, 0.f) : 0u);  \
            u.z = (g == 0) ? pk2bf(bx1, bx2) : 0u;                                 \
            u.w = (g == 0) ? pk2bf(xl0, xl1) : 0u;                                 \
            DST = __builtin_bit_cast(short8v, u);                                  \
        }
        B1BUILD(0, b1f_0) B1BUILD(1, b1f_1)
        #undef B1BUILD
        SCHED_FENCE();

        // ---- layer-2 accumulators: 8 jt x 2 rt (64 regs, AGPR) ----
        #define ACCDECL(JT) f32x4 acc_##JT##_0 = z4, acc_##JT##_1 = z4;
        ACCDECL(0) ACCDECL(1) ACCDECL(2) ACCDECL(3)
        ACCDECL(4) ACCDECL(5) ACCDECL(6) ACCDECL(7)
        #undef ACCDECL

        #define STEP(JT, RT) acc_##JT##_##RT = MFMA(af_##JT, bf_##RT, acc_##JT##_##RT)
        // per-ks region: {a1+af reads | 4 L1-MFMA | relu | pack | 16 L2-MFMA}
        #define KSBLOCK(KS) {                                                         \
            const short8v a1_0 = __builtin_bit_cast(short8v, sA1[(2*(KS)  )*64+lane]);\
            const short8v a1_1 = __builtin_bit_cast(short8v, sA1[(2*(KS)+1)*64+lane]);\
            const short8v af_0 = __builtin_bit_cast(short8v, sA2[(0*4+(KS))*64+lane]);\
            const short8v af_1 = __builtin_bit_cast(short8v, sA2[(1*4+(KS))*64+lane]);\
            const short8v af_2 = __builtin_bit_cast(short8v, sA2[(2*4+(KS))*64+lane]);\
            const short8v af_3 = __builtin_bit_cast(short8v, sA2[(3*4+(KS))*64+lane]);\
            const short8v af_4 = __builtin_bit_cast(short8v, sA2[(4*4+(KS))*64+lane]);\
            const short8v af_5 = __builtin_bit_cast(short8v, sA2[(5*4+(KS))*64+lane]);\
            const short8v af_6 = __builtin_bit_cast(short8v, sA2[(6*4+(KS))*64+lane]);\
            const short8v af_7 = __builtin_bit_cast(short8v, sA2[(7*4+(KS))*64+lane]);\
            const f32x4 h00 = relu4(MFMA(a1_0, b1f_0, z4));  /* (jt=2ks,  rt0) */     \
            const f32x4 h01 = relu4(MFMA(a1_0, b1f_1, z4));  /* (jt=2ks,  rt1) */     \
            const f32x4 h10 = relu4(MFMA(a1_1, b1f_0, z4));  /* (jt=2ks+1,rt0) */     \
            const f32x4 h11 = relu4(MFMA(a1_1, b1f_1, z4));  /* (jt=2ks+1,rt1) */     \
            uint4v u0, u1;                                                            \
            u0.x = pk2bf(h00.x, h00.y); u0.y = pk2bf(h00.z, h00.w);                   \
            u0.z = pk2bf(h10.x, h10.y); u0.w = pk2bf(h10.z, h10.w);                   \
            u1.x = pk2bf(h01.x, h01.y); u1.y = pk2bf(h01.z, h01.w);                   \
            u1.z = pk2bf(h11.x, h11.y); u1.w = pk2bf(h11.z, h11.w);                   \
            const short8v bf_0 = __builtin_bit_cast(short8v, u0);                     \
            const short8v bf_1 = __builtin_bit_cast(short8v, u1);                     \
            __builtin_amdgcn_s_setprio(1);                                            \
            STEP(0,0); STEP(0,1); STEP(1,0); STEP(1,1);                               \
            STEP(2,0); STEP(2,1); STEP(3,0); STEP(3,1);                               \
            STEP(4,0); STEP(4,1); STEP(5,0); STEP(5,1);                               \
            STEP(6,0); STEP(6,1); STEP(7,0); STEP(7,1);                               \
            __builtin_amdgcn_s_setprio(0);                                            \
            SCHED_FENCE();                                                            \
        }

        KSBLOCK(0)
        // next-tile F prefetch rides in its own tiny region
        {
            const int tn = tile + gridDim.x;
            const int nn = tn * TROWS + wid * 32 + lane;
            fv = z4;
            if (lane < 32 && tn < nTiles && nn < N) fv = ((const f32x4*)F)[nn];
        }
        KSBLOCK(1)
        KSBLOCK(2)
        KSBLOCK(3)
        #undef KSBLOCK
        #undef STEP

        // ---- layer 3: one region {b2 frags + a3f reads, 8 pack + 8 MFMA} ----
        f32x4 accY_0 = z4, accY_1 = z4;
        {
            const short8v a3f_0 = __builtin_bit_cast(short8v, sA3[0 * 64 + lane]);
            const short8v a3f_1 = __builtin_bit_cast(short8v, sA3[1 * 64 + lane]);
            const short8v a3f_2 = __builtin_bit_cast(short8v, sA3[2 * 64 + lane]);
            const short8v a3f_3 = __builtin_bit_cast(short8v, sA3[3 * 64 + lane]);
            #define L3K(KS2, JA, JB) {                                                \
                const f32x4 ba = pB2[g + 8 * (KS2)];                                  \
                const f32x4 bb = pB2[g + 8 * (KS2) + 4];                              \
                const f32x4 ha0 = relu4(acc_##JA##_0 + ba);                           \
                const f32x4 hb0 = relu4(acc_##JB##_0 + bb);                           \
                const f32x4 ha1 = relu4(acc_##JA##_1 + ba);                           \
                const f32x4 hb1 = relu4(acc_##JB##_1 + bb);                           \
                uint4v u0, u1;                                                        \
                u0.x = pk2bf(ha0.x, ha0.y); u0.y = pk2bf(ha0.z, ha0.w);               \
                u0.z = pk2bf(hb0.x, hb0.y); u0.w = pk2bf(hb0.z, hb0.w);               \
                u1.x = pk2bf(ha1.x, ha1.y); u1.y = pk2bf(ha1.z, ha1.w);               \
                u1.z = pk2bf(hb1.x, hb1.y); u1.w = pk2bf(hb1.z, hb1.w);               \
                accY_0 = MFMA(a3f_##KS2, __builtin_bit_cast(short8v, u0), accY_0);    \
                accY_1 = MFMA(a3f_##KS2, __builtin_bit_cast(short8v, u1), accY_1);    \
            }
            L3K(0, 0, 1) L3K(1, 2, 3) L3K(2, 4, 5) L3K(3, 6, 7)
            #undef L3K
        }
        SCHED_FENCE();

        // ---- epilogue: same-wave LDS transpose, lanes 0..31 finish own row ----
        if (lane < 16) {
            sY[wid * 32 +  0 + lr] = accY_0;
            sY[wid * 32 + 16 + lr] = accY_1;
        }
        {
            const f32x4 yv = sY[wid * 32 + (lane & 31)];
            const int nn = nbase + lane;
            if (lane < 32 && nn < N) {
                const float y0 = yv.x, y1 = yv.y, y2 = yv.z, y3 = yv.w;
                const float s01 = 0.5f * (y1 + y2);
                const float P00 = R00 * y0  + R01 * s01;
                const float P01 = R00 * s01 + R01 * y3;
                const float P10 = R10 * y0  + R11 * s01;
                const float P11 = R10 * s01 + R11 * y3;
                f32x4 o;
                o.x = P00 * fa + P01 * fb;   // cauchy = P @ F^T
                o.y = P00 * fc + P01 * fd;
                o.z = P10 * fa + P11 * fb;
                o.w = P10 * fc + P11 * fd;
                ((f32x4*)out)[nn] = o;
            }
        }
        SCHED_FENCE();
    }
}

extern "C" void kernel_launch(void* const* d_in, const int* in_sizes, int n_in,
                              void* d_out, int out_size, void* d_ws, size_t ws_size,
                              hipStream_t stream) {
    const float* F  = (const float*)d_in[0];
    const float* W1 = (const float*)d_in[1];
    const float* b1 = (const float*)d_in[2];
    const float* W2 = (const float*)d_in[3];
    const float* b2 = (const float*)d_in[4];
    const float* W3 = (const float*)d_in[5];
    const float* b3 = (const float*)d_in[6];
    float* out = (float*)d_out;
    const int N = in_sizes[0] / 4;

    const int nTiles = (N + TROWS - 1) / TROWS;
    int grid = nTiles < NBLK ? nTiles : NBLK;
    stress_kernel<<<dim3(grid), dim3(TPB), 0, stream>>>(F, W1, b1, W2, b2, W3, b3, out, N);
}

// Round 15
// 53.465 us; speedup vs baseline: 2.2900x; 1.0281x over previous
//
#include <hip/hip_runtime.h>
#include <hip/hip_bf16.h>
#include <math.h>

#define HID   128
#define TPB   256      // 4 waves per block, 32 rows per wave -> 128 rows per block-tile
#define TROWS 128
#define NBLK  768      // persistent grid: 3 blocks/CU

typedef __attribute__((ext_vector_type(8))) short        short8v;   // 8 bf16
typedef __attribute__((ext_vector_type(4))) float        f32x4;
typedef __attribute__((ext_vector_type(4))) unsigned int uint4v;

#define MFMA(a, b, c) __builtin_amdgcn_mfma_f32_16x16x32_bf16((a), (b), (c), 0, 0, 0)
#define SCHED_FENCE() __builtin_amdgcn_sched_barrier(0)
#define BC8(x) __builtin_bit_cast(short8v, x)

// Native packed f32->bf16 pair conversion (1 VALU inst).
__device__ __forceinline__ unsigned int pk2bf(float lo, float hi) {
    unsigned int r;
    asm("v_cvt_pk_bf16_f32 %0, %1, %2" : "=v"(r) : "v"(lo), "v"(hi));
    return r;
}
// bf16 round-trip (hi part of hi-lo split): bf16(x) in high 16 bits, 0 low.
__device__ __forceinline__ float bfhi(float x) {
    unsigned int r;
    asm("v_cvt_pk_bf16_f32 %0, %1, %2" : "=v"(r) : "v"(0.f), "v"(x));
    return __builtin_bit_cast(float, r);
}
__device__ __forceinline__ f32x4 relu4(f32x4 v) {
    f32x4 r;
    r.x = fmaxf(v.x, 0.f); r.y = fmaxf(v.y, 0.f);
    r.z = fmaxf(v.z, 0.f); r.w = fmaxf(v.w, 0.f);
    return r;
}

__global__ __launch_bounds__(TPB, 2)
void stress_kernel(const float* __restrict__ F,
                   const float* __restrict__ W1, const float* __restrict__ b1,
                   const float* __restrict__ W2, const float* __restrict__ b2,
                   const float* __restrict__ W3, const float* __restrict__ b3,
                   float* __restrict__ out, int N)
{
    // ---- LDS (~46.6 KB -> 3 blocks/CU) ----
    __shared__ uint4v sA2[2048];   // 32 KB  W2^T A-frags, slot k = 4g+(b&3)+16*(2ks+(b>>2))
    __shared__ uint4v sA1[512];    //  8 KB  layer-1 A-frags (hi-lo W1 + b1 slots)
    __shared__ uint4v sA3[256];    //  4 KB  W3^T A-frags
    __shared__ f32x4  sY[TROWS];   //  2 KB  per-wave y transpose
    __shared__ __align__(16) float sb2[HID];

    const int tid  = threadIdx.x;
    const int lane = tid & 63;
    const int wid  = tid >> 6;
    const int g    = lane >> 4;     // lane group 0..3
    const int lr   = lane & 15;

    // ---- one-time staging ----
    for (int e = tid; e < 2048; e += TPB) {
        int l = e & 63, ks = (e >> 6) & 3, jt = e >> 8;
        int gg = l >> 4;
        int j  = (l & 15) + 16 * jt;
        #define K2(B) (4 * gg + ((B) & 3) + 16 * (2 * ks + ((B) >> 2)))
        uint4v v;
        v.x = pk2bf(W2[K2(0) * HID + j], W2[K2(1) * HID + j]);
        v.y = pk2bf(W2[K2(2) * HID + j], W2[K2(3) * HID + j]);
        v.z = pk2bf(W2[K2(4) * HID + j], W2[K2(5) * HID + j]);
        v.w = pk2bf(W2[K2(6) * HID + j], W2[K2(7) * HID + j]);
        #undef K2
        sA2[e] = v;
    }
    // sA1: layer-1 A-frags. A-row j = lr+16jt; k-slot c = 8g+b:
    //   c=0..2: W1[c][j] (hi) ; c=3..5: W1-Wh (lo, pairs with xh)
    //   c=6..8: W1 (hi, pairs with xl) ; c=9: b1 ; c=10: b1-b1h ; else 0
    for (int e = tid; e < 512; e += TPB) {
        int l = e & 63, jt = e >> 6;
        int gg = l >> 4;
        int j  = (l & 15) + 16 * jt;
        float av[8];
        #pragma unroll
        for (int b = 0; b < 8; ++b) {
            int c = 8 * gg + b;
            float v;
            if      (c < 3)   v = W1[c * HID + j];
            else if (c < 6)   v = W1[(c - 3) * HID + j] - bfhi(W1[(c - 3) * HID + j]);
            else if (c < 9)   v = W1[(c - 6) * HID + j];
            else if (c == 9)  v = b1[j];
            else if (c == 10) v = b1[j] - bfhi(b1[j]);
            else              v = 0.f;
            av[b] = v;
        }
        uint4v v;
        v.x = pk2bf(av[0], av[1]); v.y = pk2bf(av[2], av[3]);
        v.z = pk2bf(av[4], av[5]); v.w = pk2bf(av[6], av[7]);
        sA1[e] = v;
    }
    // sA3: W3^T padded (slot map = layer-2 D layout)
    for (int e = tid; e < 256; e += TPB) {
        int l = e & 63, ks2 = e >> 6;
        int gg = l >> 4, t = l & 15;
        float w[8];
        #pragma unroll
        for (int b = 0; b < 8; ++b) {
            int j = 4 * gg + (b & 3) + 16 * (2 * ks2 + (b >> 2));
            w[b] = (t < 4) ? W3[j * 4 + t] : 0.f;
        }
        uint4v v;
        v.x = pk2bf(w[0], w[1]); v.y = pk2bf(w[2], w[3]);
        v.z = pk2bf(w[4], w[5]); v.w = pk2bf(w[6], w[7]);
        sA3[e] = v;
    }
    for (int i = tid; i < HID; i += TPB) sb2[i] = b2[i];
    __syncthreads();

    const f32x4* pB2 = (const f32x4*)sb2;
    const f32x4  z4  = {0.f, 0.f, 0.f, 0.f};

    // b3 fragment for accY C-in: accY reg r of lane group g holds y[t=4g+r];
    // only g==0 rows are real (W3 rows t>=4 padded 0), others stay 0.
    f32x4 b3v = z4;
    if (g == 0) b3v = *(const f32x4*)b3;

    const int nTiles = (N + TROWS - 1) / TROWS;
    const int tile0  = blockIdx.x;

    // prefetch F for the first tile (lanes 0..31 own rows)
    f32x4 fv = z4;
    {
        const int n = tile0 * TROWS + wid * 32 + lane;
        if (lane < 32 && tile0 < nTiles && n < N) fv = ((const f32x4*)F)[n];
    }

    for (int tile = tile0; tile < nTiles; tile += gridDim.x) {
        const int nbase = tile * TROWS + wid * 32;

        // ---- prologue: invariants + polar R (lanes 0..31 own rows) ----
        const float fa = fv.x, fb = fv.y, fc = fv.z, fd = fv.w;
        float x0, x1, x2, R00, R01, R10, R11;
        {
            const float J   = fa * fd - fb * fc;
            const float ss  = fa * fa + fb * fb + fc * fc + fd * fd;
            const float sgn = (J >= 0.f) ? 1.f : -1.f;
            const float r   = sqrtf(fmaxf(ss + 2.f * fabsf(J), 1e-30f));
            const float inv = 1.f / r;
            x0 = r - 2.f; x1 = ss - 1.f; x2 = J - 1.f;
            R00 = (fa + sgn * fd) * inv; R01 = (fb - sgn * fc) * inv;
            R10 = (fc - sgn * fb) * inv; R11 = (fd + sgn * fa) * inv;
        }

        // ---- layer-1 B-frags + a1(KS0) prefetch + b2 acc-init reads ----
        short8v a1A_0, a1A_1, a1B_0, a1B_1;
        short8v a3f_0, a3f_1, a3f_2, a3f_3;
        a1A_0 = BC8(sA1[0 * 64 + lane]);
        a1A_1 = BC8(sA1[1 * 64 + lane]);
        const f32x4 ba0 = pB2[g +  0], bb0 = pB2[g +  4];
        const f32x4 ba1 = pB2[g +  8], bb1 = pB2[g + 12];
        const f32x4 ba2 = pB2[g + 16], bb2 = pB2[g + 20];
        const f32x4 ba3 = pB2[g + 24], bb3 = pB2[g + 28];

        short8v b1f_0, b1f_1;
        #define B1BUILD(RT, DST) {                                                 \
            const float bx0 = __shfl(x0, (RT) * 16 + lr, 64);                      \
            const float bx1 = __shfl(x1, (RT) * 16 + lr, 64);                      \
            const float bx2 = __shfl(x2, (RT) * 16 + lr, 64);                      \
            const float xl0 = bx0 - bfhi(bx0);                                     \
            const float xl1 = bx1 - bfhi(bx1);                                     \
            const float xl2 = bx2 - bfhi(bx2);                                     \
            uint4v u;                                                              \
            u.x = (g == 0) ? pk2bf(bx0, bx1) : ((g == 1) ? pk2bf(xl2, 1.f) : 0u);  \
            u.y = (g == 0) ? pk2bf(bx2, bx0) : ((g == 1) ? pk2bf(1.f, 0.f) : 0u);  \
            u.z = (g == 0) ? pk2bf(bx1, bx2) : 0u;                                 \
            u.w = (g == 0) ? pk2bf(xl0, xl1) : 0u;                                 \
            DST = __builtin_bit_cast(short8v, u);                                  \
        }
        B1BUILD(0, b1f_0) B1BUILD(1, b1f_1)
        #undef B1BUILD
        SCHED_FENCE();

        // ---- layer-2 accumulators, C-in = b2 fragment (b2 folded into MFMA) ----
        f32x4 acc_0_0 = ba0, acc_0_1 = ba0, acc_1_0 = bb0, acc_1_1 = bb0,
              acc_2_0 = ba1, acc_2_1 = ba1, acc_3_0 = bb1, acc_3_1 = bb1,
              acc_4_0 = ba2, acc_4_1 = ba2, acc_5_0 = bb2, acc_5_1 = bb2,
              acc_6_0 = ba3, acc_6_1 = ba3, acc_7_0 = bb3, acc_7_1 = bb3;

        #define STEP(JT, RT) acc_##JT##_##RT = MFMA(af_##JT, bf_##RT, acc_##JT##_##RT)
        // per-ks region: {af reads | a1(next) prefetch | L1 MFMA | pack | L2 MFMA}
        // a1 for THIS block was prefetched last block -> no lgkm stall at head.
        #define KSBLOCK(KS, A1C0, A1C1, PF)  {                                        \
            const short8v af_0 = BC8(sA2[(0*4+(KS))*64+lane]);                        \
            const short8v af_1 = BC8(sA2[(1*4+(KS))*64+lane]);                        \
            const short8v af_2 = BC8(sA2[(2*4+(KS))*64+lane]);                        \
            const short8v af_3 = BC8(sA2[(3*4+(KS))*64+lane]);                        \
            const short8v af_4 = BC8(sA2[(4*4+(KS))*64+lane]);                        \
            const short8v af_5 = BC8(sA2[(5*4+(KS))*64+lane]);                        \
            const short8v af_6 = BC8(sA2[(6*4+(KS))*64+lane]);                        \
            const short8v af_7 = BC8(sA2[(7*4+(KS))*64+lane]);                        \
            PF;                                                                       \
            const f32x4 h00 = relu4(MFMA(A1C0, b1f_0, z4));                           \
            const f32x4 h01 = relu4(MFMA(A1C0, b1f_1, z4));                           \
            const f32x4 h10 = relu4(MFMA(A1C1, b1f_0, z4));                           \
            const f32x4 h11 = relu4(MFMA(A1C1, b1f_1, z4));                           \
            uint4v u0, u1;                                                            \
            u0.x = pk2bf(h00.x, h00.y); u0.y = pk2bf(h00.z, h00.w);                   \
            u0.z = pk2bf(h10.x, h10.y); u0.w = pk2bf(h10.z, h10.w);                   \
            u1.x = pk2bf(h01.x, h01.y); u1.y = pk2bf(h01.z, h01.w);                   \
            u1.z = pk2bf(h11.x, h11.y); u1.w = pk2bf(h11.z, h11.w);                   \
            const short8v bf_0 = __builtin_bit_cast(short8v, u0);                     \
            const short8v bf_1 = __builtin_bit_cast(short8v, u1);                     \
            __builtin_amdgcn_s_setprio(1);                                            \
            STEP(0,0); STEP(0,1); STEP(1,0); STEP(1,1);                               \
            STEP(2,0); STEP(2,1); STEP(3,0); STEP(3,1);                               \
            STEP(4,0); STEP(4,1); STEP(5,0); STEP(5,1);                               \
            STEP(6,0); STEP(6,1); STEP(7,0); STEP(7,1);                               \
            __builtin_amdgcn_s_setprio(0);                                            \
            SCHED_FENCE();                                                            \
        }

        KSBLOCK(0, a1A_0, a1A_1,
                a1B_0 = BC8(sA1[2 * 64 + lane]); a1B_1 = BC8(sA1[3 * 64 + lane]))
        // next-tile F prefetch rides in its own tiny region
        {
            const int tn = tile + gridDim.x;
            const int nn = tn * TROWS + wid * 32 + lane;
            fv = z4;
            if (lane < 32 && tn < nTiles && nn < N) fv = ((const f32x4*)F)[nn];
        }
        KSBLOCK(1, a1B_0, a1B_1,
                a1A_0 = BC8(sA1[4 * 64 + lane]); a1A_1 = BC8(sA1[5 * 64 + lane]))
        KSBLOCK(2, a1A_0, a1A_1,
                a1B_0 = BC8(sA1[6 * 64 + lane]); a1B_1 = BC8(sA1[7 * 64 + lane]))
        KSBLOCK(3, a1B_0, a1B_1,
                a3f_0 = BC8(sA3[0 * 64 + lane]); a3f_1 = BC8(sA3[1 * 64 + lane]);
                a3f_2 = BC8(sA3[2 * 64 + lane]); a3f_3 = BC8(sA3[3 * 64 + lane]))
        #undef KSBLOCK
        #undef STEP

        // ---- layer 3: {relu | pack | MFMA}; b2 already in acc, b3 in C-in ----
        f32x4 accY_0 = b3v, accY_1 = b3v;
        {
            #define L3K(KS2, JA, JB) {                                                \
                const f32x4 ha0 = relu4(acc_##JA##_0);                                \
                const f32x4 hb0 = relu4(acc_##JB##_0);                                \
                const f32x4 ha1 = relu4(acc_##JA##_1);                                \
                const f32x4 hb1 = relu4(acc_##JB##_1);                                \
                uint4v u0, u1;                                                        \
                u0.x = pk2bf(ha0.x, ha0.y); u0.y = pk2bf(ha0.z, ha0.w);               \
                u0.z = pk2bf(hb0.x, hb0.y); u0.w = pk2bf(hb0.z, hb0.w);               \
                u1.x = pk2bf(ha1.x, ha1.y); u1.y = pk2bf(ha1.z, ha1.w);               \
                u1.z = pk2bf(hb1.x, hb1.y); u1.w = pk2bf(hb1.z, hb1.w);               \
                accY_0 = MFMA(a3f_##KS2, __builtin_bit_cast(short8v, u0), accY_0);    \
                accY_1 = MFMA(a3f_##KS2, __builtin_bit_cast(short8v, u1), accY_1);    \
            }
            L3K(0, 0, 1) L3K(1, 2, 3) L3K(2, 4, 5) L3K(3, 6, 7)
            #undef L3K
        }
        SCHED_FENCE();

        // ---- epilogue: same-wave LDS transpose, lanes 0..31 finish own row ----
        if (lane < 16) {
            sY[wid * 32 +  0 + lr] = accY_0;
            sY[wid * 32 + 16 + lr] = accY_1;
        }
        {
            const f32x4 yv = sY[wid * 32 + (lane & 31)];
            const int nn = nbase + lane;
            if (lane < 32 && nn < N) {
                const float y0 = yv.x, y1 = yv.y, y2 = yv.z, y3 = yv.w;
                const float s01 = 0.5f * (y1 + y2);
                const float P00 = R00 * y0  + R01 * s01;
                const float P01 = R00 * s01 + R01 * y3;
                const float P10 = R10 * y0  + R11 * s01;
                const float P11 = R10 * s01 + R11 * y3;
                f32x4 o;
                o.x = P00 * fa + P01 * fb;   // cauchy = P @ F^T
                o.y = P00 * fc + P01 * fd;
                o.z = P10 * fa + P11 * fb;
                o.w = P10 * fc + P11 * fd;
                ((f32x4*)out)[nn] = o;
            }
        }
        SCHED_FENCE();
    }
}

extern "C" void kernel_launch(void* const* d_in, const int* in_sizes, int n_in,
                              void* d_out, int out_size, void* d_ws, size_t ws_size,
                              hipStream_t stream) {
    const float* F  = (const float*)d_in[0];
    const float* W1 = (const float*)d_in[1];
    const float* b1 = (const float*)d_in[2];
    const float* W2 = (const float*)d_in[3];
    const float* b2 = (const float*)d_in[4];
    const float* W3 = (const float*)d_in[5];
    const float* b3 = (const float*)d_in[6];
    float* out = (float*)d_out;
    const int N = in_sizes[0] / 4;

    const int nTiles = (N + TROWS - 1) / TROWS;
    int grid = nTiles < NBLK ? nTiles : NBLK;
    stress_kernel<<<dim3(grid), dim3(TPB), 0, stream>>>(F, W1, b1, W2, b2, W3, b3, out, N);
}